// Round 2
// baseline (505.665 us; speedup 1.0000x reference)
//
#include <hip/hip_runtime.h>
#include <math.h>

typedef __bf16 bf16;
typedef bf16 bf16x8 __attribute__((ext_vector_type(8)));
typedef bf16 bf16x4 __attribute__((ext_vector_type(4)));
typedef float f32x4 __attribute__((ext_vector_type(4)));

#define NROWS 16384
#define HID 2048

// ---------------- f32 -> bf16 conversion (vectorized) ----------------
__global__ __launch_bounds__(256) void cvt_kernel(const float* __restrict__ src,
                                                  bf16* __restrict__ dst, int n4) {
  int stride = gridDim.x * blockDim.x;
  for (int i = blockIdx.x * blockDim.x + threadIdx.x; i < n4; i += stride) {
    float4 v = ((const float4*)src)[i];
    bf16x4 o;
    o[0] = (bf16)v.x; o[1] = (bf16)v.y; o[2] = (bf16)v.z; o[3] = (bf16)v.w;
    ((bf16x4*)dst)[i] = o;
  }
}

// ---------------- async global->LDS helper ----------------
__device__ __forceinline__ void gload_lds16(const bf16* g, bf16* l) {
  __builtin_amdgcn_global_load_lds((const __attribute__((address_space(1))) void*)g,
                                   (__attribute__((address_space(3))) void*)l,
                                   16, 0, 0);
}

// ---------------- 128x128-tile bf16 GEMM: C = act(A * B^T + bias) ----------------
// A [M,K] bf16 row-major, B [N,K] bf16 row-major, C [M,N] bf16.
template <bool RELU>
__global__ __launch_bounds__(256) void gemm_bt(const bf16* __restrict__ A,
                                               const bf16* __restrict__ B,
                                               const float* __restrict__ bias,
                                               bf16* __restrict__ C,
                                               int M, int N, int K) {
  __shared__ bf16 Asub[128 * 32];
  __shared__ bf16 Bsub[128 * 32];
  const int tid = threadIdx.x;
  const int lane = tid & 63;
  const int w = tid >> 6;          // wave 0..3
  const int wr = w >> 1, wc = w & 1;
  const int bm = blockIdx.x, bn = blockIdx.y;
  const size_t baseA = (size_t)bm * 128 * K;
  const size_t baseB = (size_t)bn * 128 * K;

  f32x4 acc[4][4] = {};

  const int srow = lane >> 2;        // 0..15 within chunk
  const int scol = (lane & 3) * 8;   // 0,8,16,24

  for (int k0 = 0; k0 < K; k0 += 32) {
#pragma unroll
    for (int i = 0; i < 2; ++i) {
      const int chunk = i * 4 + w;               // 0..7 (each = 16 rows x 32 cols)
      const int row = chunk * 16 + srow;         // 0..127
      // LDS dest is wave-uniform base; HW scatters lane*16B. Linear layout matches.
      gload_lds16(A + baseA + (size_t)row * K + k0 + scol, &Asub[chunk * 512]);
      gload_lds16(B + baseB + (size_t)row * K + k0 + scol, &Bsub[chunk * 512]);
    }
    __syncthreads();

    bf16x8 a[4], b[4];
#pragma unroll
    for (int mi = 0; mi < 4; ++mi)
      a[mi] = *(const bf16x8*)&Asub[(wr * 64 + mi * 16 + (lane & 15)) * 32 + (lane >> 4) * 8];
#pragma unroll
    for (int ni = 0; ni < 4; ++ni)
      b[ni] = *(const bf16x8*)&Bsub[(wc * 64 + ni * 16 + (lane & 15)) * 32 + (lane >> 4) * 8];
#pragma unroll
    for (int mi = 0; mi < 4; ++mi)
#pragma unroll
      for (int ni = 0; ni < 4; ++ni)
        acc[mi][ni] = __builtin_amdgcn_mfma_f32_16x16x32_bf16(a[mi], b[ni], acc[mi][ni], 0, 0, 0);
    __syncthreads();
  }

  // epilogue: bias + optional relu, bf16 store
  const int crow0 = bm * 128 + wr * 64 + (lane >> 4) * 4;
  const int ccol0 = bn * 128 + wc * 64 + (lane & 15);
#pragma unroll
  for (int mi = 0; mi < 4; ++mi) {
#pragma unroll
    for (int ni = 0; ni < 4; ++ni) {
      const int col = ccol0 + ni * 16;
      const float bv = bias[col];
#pragma unroll
      for (int j = 0; j < 4; ++j) {
        const int row = crow0 + mi * 16 + j;
        float v = acc[mi][ni][j] + bv;
        if (RELU) v = fmaxf(v, 0.f);
        C[(size_t)row * N + col] = (bf16)v;
      }
    }
  }
}

// ---------------- fused GEMM3 (N=10) + log-softmax + gather + sum ----------------
__global__ __launch_bounds__(256) void loss_kernel(const bf16* __restrict__ h2,
                                                   const bf16* __restrict__ W3b,
                                                   const float* __restrict__ b3,
                                                   const int* __restrict__ Y,
                                                   float* __restrict__ acc) {
  __shared__ bf16 w3s[10 * HID];
  for (int i = threadIdx.x; i < 10 * HID / 8; i += 256)
    ((bf16x8*)w3s)[i] = ((const bf16x8*)W3b)[i];
  __syncthreads();

  const int lane = threadIdx.x & 63;
  const int w = threadIdx.x >> 6;
  const int nwave = gridDim.x * 4;
  float lsum = 0.f;

  for (int row = blockIdx.x * 4 + w; row < NROWS; row += nwave) {
    float p[10];
#pragma unroll
    for (int c = 0; c < 10; ++c) p[c] = 0.f;
    const bf16* hrow = h2 + (size_t)row * HID;
#pragma unroll
    for (int it = 0; it < 4; ++it) {
      const int k = it * 512 + lane * 8;
      bf16x8 hv = *(const bf16x8*)&hrow[k];
      float hf[8];
#pragma unroll
      for (int j = 0; j < 8; ++j) hf[j] = (float)hv[j];
#pragma unroll
      for (int c = 0; c < 10; ++c) {
        bf16x8 wv = *(const bf16x8*)&w3s[c * HID + k];
        float dp = 0.f;
#pragma unroll
        for (int j = 0; j < 8; ++j) dp += hf[j] * (float)wv[j];
        p[c] += dp;
      }
    }
#pragma unroll
    for (int off = 32; off; off >>= 1)
#pragma unroll
      for (int c = 0; c < 10; ++c) p[c] += __shfl_xor(p[c], off, 64);

    float lg[10], m = -1e30f;
#pragma unroll
    for (int c = 0; c < 10; ++c) { lg[c] = p[c] + b3[c]; m = fmaxf(m, lg[c]); }
    float s = 0.f;
#pragma unroll
    for (int c = 0; c < 10; ++c) s += expf(lg[c] - m);
    const float lse = m + logf(s);
    const int y = Y[row];
    float ly = 0.f;
#pragma unroll
    for (int c = 0; c < 10; ++c) ly += (c == y) ? lg[c] : 0.f;  // static indexing (no scratch)
    lsum += ly - lse;
  }
  if (lane == 0) atomicAdd(&acc[0], lsum);
}

// ---------------- sum of squares of all params (prior) ----------------
struct SqArgs { const float* p[6]; int n[6]; };

__global__ __launch_bounds__(256) void sumsq_kernel(SqArgs args, float* __restrict__ acc) {
  float s = 0.f;
  const int stride = gridDim.x * blockDim.x;
  for (int a = 0; a < 6; ++a) {
    const float* p = args.p[a];
    const int n = args.n[a];
    for (int i = blockIdx.x * blockDim.x + threadIdx.x; i < n; i += stride) {
      float v = p[i];
      s += v * v;
    }
  }
#pragma unroll
  for (int off = 32; off; off >>= 1) s += __shfl_xor(s, off, 64);
  if ((threadIdx.x & 63) == 0) atomicAdd(&acc[1], s);
}

__global__ void finalize_kernel(float* __restrict__ out, const float* __restrict__ acc,
                                double dterm) {
  out[0] = (float)((double)acc[0] - 0.5 * ((double)acc[1] / 100.0 + dterm));
}

// ---------------- launch ----------------
extern "C" void kernel_launch(void* const* d_in, const int* in_sizes, int n_in,
                              void* d_out, int out_size, void* d_ws, size_t ws_size,
                              hipStream_t stream) {
  const float* X  = (const float*)d_in[0];
  const int*   Y  = (const int*)d_in[1];
  const float* W1 = (const float*)d_in[2];
  const float* b1 = (const float*)d_in[3];
  const float* W2 = (const float*)d_in[4];
  const float* b2 = (const float*)d_in[5];
  const float* W3 = (const float*)d_in[6];
  const float* b3 = (const float*)d_in[7];
  float* out = (float*)d_out;

  char* ws = (char*)d_ws;
  size_t off = 0;
  auto alloc = [&](size_t bytes) -> void* {
    void* p = ws + off;
    off += (bytes + 255) & ~(size_t)255;
    return p;
  };
  bf16* Xb  = (bf16*)alloc((size_t)NROWS * 1024 * 2);
  bf16* W1b = (bf16*)alloc((size_t)HID * 1024 * 2);
  bf16* W2b = (bf16*)alloc((size_t)HID * HID * 2);
  bf16* W3b = (bf16*)alloc((size_t)10 * HID * 2);
  bf16* h1  = (bf16*)alloc((size_t)NROWS * HID * 2);
  bf16* h2  = (bf16*)alloc((size_t)NROWS * HID * 2);
  float* acc = (float*)alloc(256);

  hipMemsetAsync(acc, 0, 16, stream);

  auto cvt = [&](const float* s, bf16* d, int n) {
    int n4 = n / 4;
    int grid = (n4 + 255) / 256;
    if (grid > 4096) grid = 4096;
    cvt_kernel<<<grid, 256, 0, stream>>>(s, d, n4);
  };
  cvt(X,  Xb,  NROWS * 1024);
  cvt(W1, W1b, HID * 1024);
  cvt(W2, W2b, HID * HID);
  cvt(W3, W3b, 10 * HID);

  SqArgs sq;
  sq.p[0] = W1; sq.n[0] = in_sizes[2];
  sq.p[1] = b1; sq.n[1] = in_sizes[3];
  sq.p[2] = W2; sq.n[2] = in_sizes[4];
  sq.p[3] = b2; sq.n[3] = in_sizes[5];
  sq.p[4] = W3; sq.n[4] = in_sizes[6];
  sq.p[5] = b3; sq.n[5] = in_sizes[7];
  sumsq_kernel<<<512, 256, 0, stream>>>(sq, acc);

  // GEMM1: h1 = relu(X[16384,1024] * W1[2048,1024]^T + b1)
  gemm_bt<true><<<dim3(NROWS / 128, HID / 128), 256, 0, stream>>>(
      Xb, W1b, b1, h1, NROWS, HID, 1024);
  // GEMM2: h2 = relu(h1 * W2[2048,2048]^T + b2)
  gemm_bt<true><<<dim3(NROWS / 128, HID / 128), 256, 0, stream>>>(
      h1, W2b, b2, h2, NROWS, HID, HID);

  loss_kernel<<<256, 256, 0, stream>>>(h2, W3b, b3, Y, acc);

  long long d = 0;
  for (int i = 2; i < 8; ++i) d += in_sizes[i];
  double dterm = (double)d * log(2.0 * M_PI * 100.0);
  finalize_kernel<<<1, 1, 0, stream>>>(out, acc, dterm);
}

// Round 4
// 436.652 us; speedup vs baseline: 1.1581x; 1.1581x over previous
//
#include <hip/hip_runtime.h>
#include <math.h>

typedef __bf16 bf16;
typedef bf16 bf16x8 __attribute__((ext_vector_type(8)));
typedef bf16 bf16x4 __attribute__((ext_vector_type(4)));
typedef float f32x4 __attribute__((ext_vector_type(4)));

#define NROWS 16384
#define HID 2048

// ---------------- f32 -> bf16 conversion (vectorized) ----------------
__global__ __launch_bounds__(256) void cvt_kernel(const float* __restrict__ src,
                                                  bf16* __restrict__ dst, int n4) {
  int stride = gridDim.x * blockDim.x;
  for (int i = blockIdx.x * blockDim.x + threadIdx.x; i < n4; i += stride) {
    float4 v = ((const float4*)src)[i];
    bf16x4 o;
    o[0] = (bf16)v.x; o[1] = (bf16)v.y; o[2] = (bf16)v.z; o[3] = (bf16)v.w;
    ((bf16x4*)dst)[i] = o;
  }
}

// ---------------- async global->LDS helper ----------------
__device__ __forceinline__ void gload_lds16(const bf16* g, bf16* l) {
  __builtin_amdgcn_global_load_lds((const __attribute__((address_space(1))) void*)g,
                                   (__attribute__((address_space(3))) void*)l,
                                   16, 0, 0);
}

// =====================================================================
// 256x256-tile bf16 GEMM, BK=32, 4-deep LDS pipeline with counted vmcnt.
// C = act(A * B^T + bias).  A [M,K], B [N,K] row-major bf16, C [M,N] bf16.
// Grid: 512 blocks (64 bm x 8 bn), 512 threads (8 waves, 2M x 4N).
// LDS: 4 bufs x (A 256x32 + B 256x32) bf16 = 128 KiB (dynamic).
// Swizzle: slot permutation k_p = k ^ ((row>>1)&3) applied on BOTH the
// global-source side (pre-swizzled per-lane address; LDS dest stays linear
// per global_load_lds rules) and the ds_read side (same involution).
// =====================================================================
template <int K, bool RELU>
__global__ __launch_bounds__(512) void gemm256(const bf16* __restrict__ A,
                                               const bf16* __restrict__ B,
                                               const float* __restrict__ bias,
                                               bf16* __restrict__ C, int N) {
  extern __shared__ bf16 smem[];
  constexpr int NT = K / 32;
  const int tid = threadIdx.x;
  const int lane = tid & 63;
  const int w = tid >> 6;          // wave 0..7
  const int wr = w >> 2, wc = w & 3;

  // XCD-aware swizzle: 512 blocks, XCD c gets bm in [c*8,c*8+8) x all 8 bn.
  const int c = blockIdx.x & 7, l = blockIdx.x >> 3;
  const int bm = c * 8 + (l >> 3);
  const int bn = l & 7;

  const bf16* Abase = A + (size_t)bm * 256 * K;
  const bf16* Bbase = B + (size_t)bn * 256 * K;

  // ---- staging source offsets (global side of the swizzle) ----
  // physical slot p = o*512 + tid; row = p>>2, k_p = p&3, k = k_p ^ ((row>>1)&3)
  const int r0 = tid >> 2;          // rows 0..127   (op 0)
  const int r1 = r0 + 128;          // rows 128..255 (op 1)
  const int kp = tid & 3;
  const size_t offS0 = (size_t)r0 * K + ((kp ^ ((r0 >> 1) & 3)) * 8);
  const size_t offS1 = (size_t)r1 * K + ((kp ^ ((r1 >> 1) & 3)) * 8);

  // ---- read offsets (same involution), elems within one buffer ----
  int offRA[8], offRB[4];
  const int kk = lane >> 4;         // logical k-slot 0..3
#pragma unroll
  for (int mi = 0; mi < 8; ++mi) {
    const int r = wr * 128 + mi * 16 + (lane & 15);
    offRA[mi] = (r * 4 + (kk ^ ((r >> 1) & 3))) * 8;
  }
#pragma unroll
  for (int ni = 0; ni < 4; ++ni) {
    const int r = wc * 64 + ni * 16 + (lane & 15);
    offRB[ni] = (r * 4 + (kk ^ ((r >> 1) & 3))) * 8 + 8192;
  }

  f32x4 acc[8][4] = {};

#define STAGE(t, b)                                                   \
  {                                                                   \
    const bf16* As = Abase + (size_t)(t) * 32;                        \
    const bf16* Bs = Bbase + (size_t)(t) * 32;                        \
    bf16* d = smem + (b) * 16384 + w * 512; /* wave-uniform base */   \
    gload_lds16(As + offS0, d);                                       \
    gload_lds16(As + offS1, d + 4096);                                \
    gload_lds16(Bs + offS0, d + 8192);                                \
    gload_lds16(Bs + offS1, d + 12288);                               \
  }

  // prologue: tiles 0,1,2 in flight (12 loads); wait oldest 4 = tile 0
  STAGE(0, 0); STAGE(1, 1); STAGE(2, 2);
  asm volatile("s_waitcnt vmcnt(8)" ::: "memory");
  __builtin_amdgcn_s_barrier();
  asm volatile("" ::: "memory");

  for (int t = 0; t < NT; ++t) {
    if (t + 3 < NT) STAGE(t + 3, (t + 3) & 3);   // buf last read at iter t-1

    const bf16* base = smem + (t & 3) * 16384;
    bf16x8 af[8], bfr[4];
#pragma unroll
    for (int mi = 0; mi < 8; ++mi) af[mi] = *(const bf16x8*)(base + offRA[mi]);
#pragma unroll
    for (int ni = 0; ni < 4; ++ni) bfr[ni] = *(const bf16x8*)(base + offRB[ni]);

    __builtin_amdgcn_s_setprio(1);
#pragma unroll
    for (int mi = 0; mi < 8; ++mi)
#pragma unroll
      for (int ni = 0; ni < 4; ++ni)
        acc[mi][ni] = __builtin_amdgcn_mfma_f32_16x16x32_bf16(af[mi], bfr[ni], acc[mi][ni], 0, 0, 0);
    __builtin_amdgcn_s_setprio(0);
    asm volatile("" ::: "memory");

    if (t + 1 < NT) {
      // wait until tile t+1 landed; leave younger tiles in flight (never 0 mid-loop)
      if (t + 3 < NT)      asm volatile("s_waitcnt vmcnt(8)" ::: "memory");
      else if (t + 2 < NT) asm volatile("s_waitcnt vmcnt(4)" ::: "memory");
      else                 asm volatile("s_waitcnt vmcnt(0)" ::: "memory");
      __builtin_amdgcn_s_barrier();
      asm volatile("" ::: "memory");
    }
  }
#undef STAGE

  // epilogue: bias + optional relu, bf16 store
  const int crow0 = bm * 256 + wr * 128 + (lane >> 4) * 4;
  const int ccol0 = bn * 256 + wc * 64 + (lane & 15);
#pragma unroll
  for (int mi = 0; mi < 8; ++mi) {
#pragma unroll
    for (int ni = 0; ni < 4; ++ni) {
      const int col = ccol0 + ni * 16;
      const float bv = bias[col];
#pragma unroll
      for (int j = 0; j < 4; ++j) {
        const int row = crow0 + mi * 16 + j;
        float v = acc[mi][ni][j] + bv;
        if (RELU) v = fmaxf(v, 0.f);
        C[(size_t)row * N + col] = (bf16)v;
      }
    }
  }
}

// ---------------- fused GEMM3 (N=10) + log-softmax + gather + sum ----------------
__global__ __launch_bounds__(256) void loss_kernel(const bf16* __restrict__ h2,
                                                   const bf16* __restrict__ W3b,
                                                   const float* __restrict__ b3,
                                                   const int* __restrict__ Y,
                                                   float* __restrict__ acc) {
  __shared__ bf16 w3s[10 * HID];
  for (int i = threadIdx.x; i < 10 * HID / 8; i += 256)
    ((bf16x8*)w3s)[i] = ((const bf16x8*)W3b)[i];
  __syncthreads();

  const int lane = threadIdx.x & 63;
  const int w = threadIdx.x >> 6;
  const int nwave = gridDim.x * 4;
  float lsum = 0.f;

  for (int row = blockIdx.x * 4 + w; row < NROWS; row += nwave) {
    float p[10];
#pragma unroll
    for (int c = 0; c < 10; ++c) p[c] = 0.f;
    const bf16* hrow = h2 + (size_t)row * HID;
#pragma unroll
    for (int it = 0; it < 4; ++it) {
      const int k = it * 512 + lane * 8;
      bf16x8 hv = *(const bf16x8*)&hrow[k];
      float hf[8];
#pragma unroll
      for (int j = 0; j < 8; ++j) hf[j] = (float)hv[j];
#pragma unroll
      for (int c = 0; c < 10; ++c) {
        bf16x8 wv = *(const bf16x8*)&w3s[c * HID + k];
        float dp = 0.f;
#pragma unroll
        for (int j = 0; j < 8; ++j) dp += hf[j] * (float)wv[j];
        p[c] += dp;
      }
    }
#pragma unroll
    for (int off = 32; off; off >>= 1)
#pragma unroll
      for (int c = 0; c < 10; ++c) p[c] += __shfl_xor(p[c], off, 64);

    float lg[10], m = -1e30f;
#pragma unroll
    for (int c = 0; c < 10; ++c) { lg[c] = p[c] + b3[c]; m = fmaxf(m, lg[c]); }
    float s = 0.f;
#pragma unroll
    for (int c = 0; c < 10; ++c) s += expf(lg[c] - m);
    const float lse = m + logf(s);
    const int y = Y[row];
    float ly = 0.f;
#pragma unroll
    for (int c = 0; c < 10; ++c) ly += (c == y) ? lg[c] : 0.f;
    lsum += ly - lse;
  }
  if (lane == 0) atomicAdd(&acc[0], lsum);
}

// ---------------- sum of squares of all params (prior) ----------------
struct SqArgs { const float* p[6]; int n[6]; };

__global__ __launch_bounds__(256) void sumsq_kernel(SqArgs args, float* __restrict__ acc) {
  float s = 0.f;
  const int stride = gridDim.x * blockDim.x;
  for (int a = 0; a < 6; ++a) {
    const float* p = args.p[a];
    const int n = args.n[a];
    for (int i = blockIdx.x * blockDim.x + threadIdx.x; i < n; i += stride) {
      float v = p[i];
      s += v * v;
    }
  }
#pragma unroll
  for (int off = 32; off; off >>= 1) s += __shfl_xor(s, off, 64);
  if ((threadIdx.x & 63) == 0) atomicAdd(&acc[1], s);
}

__global__ void finalize_kernel(float* __restrict__ out, const float* __restrict__ acc,
                                double dterm) {
  out[0] = (float)((double)acc[0] - 0.5 * ((double)acc[1] / 100.0 + dterm));
}

// ---------------- launch ----------------
extern "C" void kernel_launch(void* const* d_in, const int* in_sizes, int n_in,
                              void* d_out, int out_size, void* d_ws, size_t ws_size,
                              hipStream_t stream) {
  const float* X  = (const float*)d_in[0];
  const int*   Y  = (const int*)d_in[1];
  const float* W1 = (const float*)d_in[2];
  const float* b1 = (const float*)d_in[3];
  const float* W2 = (const float*)d_in[4];
  const float* b2 = (const float*)d_in[5];
  const float* W3 = (const float*)d_in[6];
  const float* b3 = (const float*)d_in[7];
  float* out = (float*)d_out;

  char* ws = (char*)d_ws;
  size_t off = 0;
  auto alloc = [&](size_t bytes) -> void* {
    void* p = ws + off;
    off += (bytes + 255) & ~(size_t)255;
    return p;
  };
  bf16* Xb  = (bf16*)alloc((size_t)NROWS * 1024 * 2);
  bf16* W1b = (bf16*)alloc((size_t)HID * 1024 * 2);
  bf16* W2b = (bf16*)alloc((size_t)HID * HID * 2);
  bf16* W3b = (bf16*)alloc((size_t)10 * HID * 2);
  bf16* h1  = (bf16*)alloc((size_t)NROWS * HID * 2);
  bf16* h2  = (bf16*)alloc((size_t)NROWS * HID * 2);
  float* acc = (float*)alloc(256);

  hipMemsetAsync(acc, 0, 16, stream);

  auto cvt = [&](const float* s, bf16* d, int n) {
    int n4 = n / 4;
    int grid = (n4 + 255) / 256;
    if (grid > 4096) grid = 4096;
    cvt_kernel<<<grid, 256, 0, stream>>>(s, d, n4);
  };
  cvt(X,  Xb,  NROWS * 1024);
  cvt(W1, W1b, HID * 1024);
  cvt(W2, W2b, HID * HID);
  cvt(W3, W3b, 10 * HID);

  SqArgs sq;
  sq.p[0] = W1; sq.n[0] = in_sizes[2];
  sq.p[1] = b1; sq.n[1] = in_sizes[3];
  sq.p[2] = W2; sq.n[2] = in_sizes[4];
  sq.p[3] = b2; sq.n[3] = in_sizes[5];
  sq.p[4] = W3; sq.n[4] = in_sizes[6];
  sq.p[5] = b3; sq.n[5] = in_sizes[7];
  sumsq_kernel<<<512, 256, 0, stream>>>(sq, acc);

  // allow 128 KiB dynamic LDS (idempotent; not a stream op, capture-safe)
  hipFuncSetAttribute((const void*)gemm256<1024, true>,
                      hipFuncAttributeMaxDynamicSharedMemorySize, 131072);
  hipFuncSetAttribute((const void*)gemm256<2048, true>,
                      hipFuncAttributeMaxDynamicSharedMemorySize, 131072);

  // GEMM1: h1 = relu(X[16384,1024] * W1[2048,1024]^T + b1)
  gemm256<1024, true><<<512, 512, 131072, stream>>>(Xb, W1b, b1, h1, HID);
  // GEMM2: h2 = relu(h1 * W2[2048,2048]^T + b2)
  gemm256<2048, true><<<512, 512, 131072, stream>>>(h1, W2b, b2, h2, HID);

  loss_kernel<<<256, 256, 0, stream>>>(h2, W3b, b3, Y, acc);

  long long d = 0;
  for (int i = 2; i < 8; ++i) d += in_sizes[i];
  double dterm = (double)d * log(2.0 * M_PI * 100.0);
  finalize_kernel<<<1, 1, 0, stream>>>(out, acc, dterm);
}